// Round 1
// baseline (1273.933 us; speedup 1.0000x reference)
//
#include <hip/hip_runtime.h>
#include <math.h>

#define NN   100000
#define NE   1000000
#define CIN  128
#define COUT 64
#define BN_EPS 1e-5f

// ---- workspace layout (float offsets) ----
#define Y1_OFF    0
#define T_OFF     (NN*COUT)                 // 6,400,000
#define W1P_OFF   (2*NN*COUT)               // 12,800,000
#define C1_OFF    (W1P_OFF + 3*CIN*COUT)    // + 24576
#define INSUM_OFF (C1_OFF + 3*COUT)         // + 192
#define INSQ_OFF  (INSUM_OFF + CIN)
#define OSUM_OFF  (INSQ_OFF + CIN)          // 3*64
#define OSQ_OFF   (OSUM_OFF + 3*COUT)
#define SCALE_OFF (OSQ_OFF + 3*COUT)
#define SHIFT_OFF (SCALE_OFF + CIN)
#define OBNS_OFF  (SHIFT_OFF + CIN)         // 3*64
#define OBNB_OFF  (OBNS_OFF + 3*COUT)       // 3*64
#define ZERO_OFF  INSUM_OFF
#define ZERO_CNT  (2*CIN + 6*COUT)          // 640 floats

// ---- input BN: per-channel sum/sumsq over nodes ----
__global__ __launch_bounds__(256) void k_in_stats(const float* __restrict__ x,
                                                  float* __restrict__ ws) {
    int tid = blockIdx.x * blockDim.x + threadIdx.x;
    int c = tid & (CIN - 1);
    int r0 = tid >> 7;
    int rstride = (gridDim.x * blockDim.x) >> 7;
    float s = 0.f, ss = 0.f;
    for (int r = r0; r < NN; r += rstride) {
        float v = x[(size_t)r * CIN + c];
        s += v; ss += v * v;
    }
    unsafeAtomicAdd(&ws[INSUM_OFF + c], s);
    unsafeAtomicAdd(&ws[INSQ_OFF + c], ss);
}

__global__ void k_in_finalize(const float* __restrict__ g, const float* __restrict__ b,
                              float* __restrict__ ws) {
    int c = threadIdx.x;   // 128 threads
    float mu  = ws[INSUM_OFF + c] * (1.f / NN);
    float var = ws[INSQ_OFF + c] * (1.f / NN) - mu * mu;
    float sc  = g[c] * rsqrtf(var + BN_EPS);
    ws[SCALE_OFF + c] = sc;
    ws[SHIFT_OFF + c] = b[c] - mu * sc;
}

// fold input-BN scale into W1:  W1'[i][k][o] = scale[k]*W1[i][k][o]
__global__ void k_fold(const float* __restrict__ W1, float* __restrict__ ws) {
    int idx = blockIdx.x * blockDim.x + threadIdx.x;   // < 3*128*64
    int k = (idx >> 6) & (CIN - 1);
    ws[W1P_OFF + idx] = ws[SCALE_OFF + k] * W1[idx];
}

// c1[i][o] = sum_k shift[k]*W1[i][k][o]   (the per-row constant inside y1)
__global__ void k_c1(const float* __restrict__ W1, float* __restrict__ ws) {
    int i = blockIdx.x, o = threadIdx.x;   // 3 blocks x 64
    float acc = 0.f;
    for (int k = 0; k < CIN; ++k)
        acc = fmaf(ws[SHIFT_OFF + k], W1[i * CIN * COUT + k * COUT + o], acc);
    ws[C1_OFF + i * COUT + o] = acc;
}

// y1 = x @ W1' + c1 ; also t = y1 (scatter accumulator init)
__global__ __launch_bounds__(256, 2) void k_gemm1(const float* __restrict__ x,
                                                  float* __restrict__ ws, int br) {
    const float* __restrict__ W1p = ws + W1P_OFF + br * CIN * COUT;
    const float* __restrict__ c1  = ws + C1_OFF + br * COUT;
    float* __restrict__ y1 = ws + Y1_OFF;
    float* __restrict__ t  = ws + T_OFF;
    int lane = threadIdx.x & 63;
    int wave = (blockIdx.x * blockDim.x + threadIdx.x) >> 6;
    int nw   = (gridDim.x * blockDim.x) >> 6;
    float wk[CIN];
    #pragma unroll
    for (int k = 0; k < CIN; ++k) wk[k] = W1p[k * COUT + lane];
    float c1v = c1[lane];
    for (int n = wave; n < NN; n += nw) {
        const float* __restrict__ xr =
            x + (size_t)__builtin_amdgcn_readfirstlane(n) * CIN;
        float a0 = 0.f, a1 = 0.f, a2 = 0.f, a3 = 0.f;
        #pragma unroll
        for (int k = 0; k < CIN; k += 4) {
            a0 = fmaf(xr[k],     wk[k],     a0);
            a1 = fmaf(xr[k + 1], wk[k + 1], a1);
            a2 = fmaf(xr[k + 2], wk[k + 2], a2);
            a3 = fmaf(xr[k + 3], wk[k + 3], a3);
        }
        float v = (a0 + a1) + (a2 + a3) + c1v;
        size_t off = (size_t)n * COUT + lane;
        y1[off] = v;
        t[off]  = v;
    }
}

// t[dst] += y1[src]  (wave per edge, lane = channel)
__global__ __launch_bounds__(256) void k_scatter(const int* __restrict__ ei,
                                                 float* __restrict__ ws) {
    const float* __restrict__ y1 = ws + Y1_OFF;
    float* __restrict__ t = ws + T_OFF;
    int lane = threadIdx.x & 63;
    int wave = (blockIdx.x * blockDim.x + threadIdx.x) >> 6;
    int nw   = (gridDim.x * blockDim.x) >> 6;
    for (int e = wave; e < NE; e += nw) {
        int ee = __builtin_amdgcn_readfirstlane(e);
        int s = ei[ee];
        int d = ei[NE + ee];
        float v = y1[(size_t)s * COUT + lane];
        unsafeAtomicAdd(&t[(size_t)d * COUT + lane], v);
    }
}

// h2 = relu(t + b1) @ W2 + b2 -> d_out section; accumulate BN stats
__global__ __launch_bounds__(256, 4) void k_layer2(const float* __restrict__ W2all,
                                                   const float* __restrict__ b1all,
                                                   const float* __restrict__ b2all,
                                                   float* __restrict__ out,
                                                   float* __restrict__ ws, int br) {
    const float* __restrict__ W2 = W2all + br * COUT * COUT;
    const float* __restrict__ t  = ws + T_OFF;
    float* osum = ws + OSUM_OFF + br * COUT;
    float* osq  = ws + OSQ_OFF  + br * COUT;
    int lane = threadIdx.x & 63;
    int wave = (blockIdx.x * blockDim.x + threadIdx.x) >> 6;
    int nw   = (gridDim.x * blockDim.x) >> 6;
    float w2k[COUT];
    #pragma unroll
    for (int j = 0; j < COUT; ++j) w2k[j] = W2[j * COUT + lane];
    float b1v = b1all[br * COUT + lane];
    float b2v = b2all[br * COUT + lane];
    float ls = 0.f, lss = 0.f;
    for (int n = wave; n < NN; n += nw) {
        float t1 = fmaxf(t[(size_t)n * COUT + lane] + b1v, 0.f);
        int t1i = __float_as_int(t1);
        float a0 = b2v, a1 = 0.f, a2 = 0.f, a3 = 0.f;
        #pragma unroll
        for (int j = 0; j < COUT; j += 4) {
            a0 = fmaf(__int_as_float(__builtin_amdgcn_readlane(t1i, j)),     w2k[j],     a0);
            a1 = fmaf(__int_as_float(__builtin_amdgcn_readlane(t1i, j + 1)), w2k[j + 1], a1);
            a2 = fmaf(__int_as_float(__builtin_amdgcn_readlane(t1i, j + 2)), w2k[j + 2], a2);
            a3 = fmaf(__int_as_float(__builtin_amdgcn_readlane(t1i, j + 3)), w2k[j + 3], a3);
        }
        float acc = (a0 + a1) + (a2 + a3);
        out[(size_t)n * COUT + lane] = acc;
        ls += acc; lss += acc * acc;
    }
    unsafeAtomicAdd(&osum[lane], ls);
    unsafeAtomicAdd(&osq[lane], lss);
}

__global__ void k_obn_final(const float* __restrict__ g, const float* __restrict__ b,
                            float* __restrict__ ws, int br) {
    int o = threadIdx.x;   // 64 threads
    float mu  = ws[OSUM_OFF + br * COUT + o] * (1.f / NN);
    float var = ws[OSQ_OFF  + br * COUT + o] * (1.f / NN) - mu * mu;
    float sc  = g[br * COUT + o] * rsqrtf(var + BN_EPS);
    ws[OBNS_OFF + br * COUT + o] = sc;
    ws[OBNB_OFF + br * COUT + o] = b[br * COUT + o] - mu * sc;
}

// y = tanh(sc[c]*h2 + sh[c]) in-place on d_out section
__global__ __launch_bounds__(256) void k_apply(float* __restrict__ out,
                                               const float* __restrict__ ws, int br) {
    const float* __restrict__ sc = ws + OBNS_OFF + br * COUT;
    const float* __restrict__ sh = ws + OBNB_OFF + br * COUT;
    int idx = blockIdx.x * blockDim.x + threadIdx.x;
    int stride = gridDim.x * blockDim.x;
    const int total = NN * COUT / 4;
    float4* o4 = (float4*)out;
    for (int v = idx; v < total; v += stride) {
        int c = (v & 15) * 4;
        float4 f = o4[v];
        f.x = tanhf(fmaf(f.x, sc[c],     sh[c]));
        f.y = tanhf(fmaf(f.y, sc[c + 1], sh[c + 1]));
        f.z = tanhf(fmaf(f.z, sc[c + 2], sh[c + 2]));
        f.w = tanhf(fmaf(f.w, sc[c + 3], sh[c + 3]));
        o4[v] = f;
    }
}

extern "C" void kernel_launch(void* const* d_in, const int* in_sizes, int n_in,
                              void* d_out, int out_size, void* d_ws, size_t ws_size,
                              hipStream_t stream) {
    const float* x   = (const float*)d_in[0];
    const int*   eip = (const int*)d_in[1];
    const int*   eis = (const int*)d_in[2];
    const int*   eiv = (const int*)d_in[3];
    const float* ig  = (const float*)d_in[4];
    const float* ib  = (const float*)d_in[5];
    const float* W1  = (const float*)d_in[6];
    const float* b1  = (const float*)d_in[7];
    const float* W2  = (const float*)d_in[8];
    const float* b2  = (const float*)d_in[9];
    const float* bng = (const float*)d_in[10];
    const float* bnb = (const float*)d_in[11];
    float* out = (float*)d_out;
    float* ws  = (float*)d_ws;

    hipMemsetAsync(ws + ZERO_OFF, 0, ZERO_CNT * sizeof(float), stream);
    k_in_stats<<<256, 256, 0, stream>>>(x, ws);
    k_in_finalize<<<1, 128, 0, stream>>>(ig, ib, ws);
    k_fold<<<96, 256, 0, stream>>>(W1, ws);
    k_c1<<<3, 64, 0, stream>>>(W1, ws);

    const int* edges[3] = {eip, eis, eiv};
    for (int br = 0; br < 3; ++br) {
        k_gemm1<<<1024, 256, 0, stream>>>(x, ws, br);
        k_scatter<<<2048, 256, 0, stream>>>(edges[br], ws);
        k_layer2<<<1024, 256, 0, stream>>>(W2, b1, b2,
                                           out + (size_t)br * NN * COUT, ws, br);
        k_obn_final<<<1, 64, 0, stream>>>(bng, bnb, ws, br);
        k_apply<<<2048, 256, 0, stream>>>(out + (size_t)br * NN * COUT, ws, br);
    }
}